// Round 21
// baseline (82.208 us; speedup 1.0000x reference)
//
#include <hip/hip_runtime.h>
#include <hip/hip_bf16.h>

// Problem: B=2, T=256, IN_DIM=512, OUT_DIM=256, H=8, TEMP=1, BN_EPS=1e-5
// ROUND 21: merge k3's GEMM2 (x@W3^T, depends only on k0) into k1a's grid
// (blocks 2560..2591), like the k2m merge. k3 -> 128 blocks (P2@M only).
#define B_ 2
#define T_ 256
#define D_ 512
#define O_ 256
#define H_ 8

typedef __attribute__((ext_vector_type(4))) float f32x4;
typedef __attribute__((ext_vector_type(8))) short bf16x8;
typedef unsigned short u16;
typedef unsigned int u32;

__device__ __forceinline__ float b2f(u16 u) {
    u32 t = ((u32)u) << 16;
    return __builtin_bit_cast(float, t);
}
__device__ __forceinline__ u16 f2b(float f) {
    u32 u = __builtin_bit_cast(u32, f);
    u32 r = (u + 0x7FFFu + ((u >> 16) & 1u)) >> 16;  // RNE
    return (u16)r;
}
__device__ __forceinline__ u32 cvtpk(float lo, float hi) {
    u32 r;
    asm("v_cvt_pk_bf16_f32 %0, %1, %2" : "=v"(r) : "v"(lo), "v"(hi));
    return r;
}
__device__ __forceinline__ float fast_tanh(float x) {
    float ax = fabsf(x);
    float e = __expf(-2.f * ax);
    float r = (1.f - e) / (1.f + e);
    return x < 0.f ? -r : r;
}
__device__ __forceinline__ uint4 ld8f2b(const float* __restrict__ p) {
    f32x4 a = *reinterpret_cast<const f32x4*>(p);
    f32x4 b = *reinterpret_cast<const f32x4*>(p + 4);
    uint4 pk;
    pk.x = cvtpk(a[0], a[1]);
    pk.y = cvtpk(a[2], a[3]);
    pk.z = cvtpk(b[0], b[1]);
    pk.w = cvtpk(b[2], b[3]);
    return pk;
}
__device__ __forceinline__ void gload16(const void* g, void* l) {
    __builtin_amdgcn_global_load_lds(
        (const __attribute__((address_space(1))) unsigned int*)g,
        (__attribute__((address_space(3))) unsigned int*)l, 16, 0, 0);
}

// ---------- K0: Xbf (bx<64), W2t (64..191), boundary scan (192..193) ----------
__global__ void k0_prep(const float* __restrict__ x, const float* __restrict__ W2,
                        const int* __restrict__ bnd,
                        u16* __restrict__ Xbf, u16* __restrict__ W2t,
                        int* __restrict__ scan_g) {
    const int tid = threadIdx.x;
    if (blockIdx.x < 64) {
        int base = (blockIdx.x * 256 + tid) * 16;
        uint4 o0 = ld8f2b(x + base);
        uint4 o1 = ld8f2b(x + base + 8);
        *reinterpret_cast<uint4*>(Xbf + base) = o0;
        *reinterpret_cast<uint4*>(Xbf + base + 8) = o1;
        return;
    }
    if (blockIdx.x >= 192) {
        const int b = blockIdx.x - 192;
        __shared__ int sc[256];
        sc[tid] = bnd[b * 256 + tid];
        __syncthreads();
        for (int off = 1; off < 256; off <<= 1) {
            int v = (tid >= off) ? sc[tid - off] : 0;
            __syncthreads();
            sc[tid] += v;
            __syncthreads();
        }
        scan_g[b * 256 + tid] = sc[tid];
        return;
    }
    const int bx2 = blockIdx.x - 64;
    const int o0 = (bx2 >> 3) * 16;
    const int dc = bx2 & 7;
    __shared__ u16 TL[8192];
    #pragma unroll
    for (int c = 0; c < 8; ++c) {
        int i = tid * 32 + c * 4;
        int r = i >> 9, rem = i & 511;
        f32x4 v = *reinterpret_cast<const f32x4*>(
            W2 + (size_t)(o0 + r) * 4096 + dc * 512 + rem);
        int dd = rem >> 3, h0 = rem & 7;
        TL[(h0 + 0) * 1024 + r * 64 + dd] = f2b(v[0]);
        TL[(h0 + 1) * 1024 + r * 64 + dd] = f2b(v[1]);
        TL[(h0 + 2) * 1024 + r * 64 + dd] = f2b(v[2]);
        TL[(h0 + 3) * 1024 + r * 64 + dd] = f2b(v[3]);
    }
    __syncthreads();
    #pragma unroll
    for (int c = 0; c < 4; ++c) {
        int jj = tid * 32 + c * 8;
        int h = jj >> 10, r = (jj >> 6) & 15, dd = jj & 63;
        *reinterpret_cast<uint4*>(W2t + (size_t)(h * 256 + o0 + r) * 512 + dc * 64 + dd) =
            *reinterpret_cast<const uint4*>(&TL[jj]);
    }
}

// ---------- K1a (+K2m, +GEMM2): <2048 attention; 2048..2559 M-GEMM; >=2560 x@W3^T ----------
__launch_bounds__(256, 4)
__global__ void k1a_att(const u16* __restrict__ Xbf, const float* __restrict__ xf,
                        const float* __restrict__ Wap, const float* __restrict__ bap,
                        const float* __restrict__ aw, u16* __restrict__ attp16,
                        const u16* __restrict__ W2t, u16* __restrict__ M,
                        const float* __restrict__ W3, float* __restrict__ part)
{
    __shared__ __align__(16) u16 XL[256 * 64];   // 32 KB
    __shared__ __align__(16) u16 WL[64 * 64];    // 8 KB

    const int tid = threadIdx.x;
    const int w = tid >> 6;
    const int l = tid & 63;
    const int l15 = l & 15;
    const int lgp = l >> 4;
    const int srow_off = (l >> 3);
    const int scol = ((l & 7) ^ ((l >> 3) & 7)) * 8;

    if (blockIdx.x >= 2560) {
        // ===== GEMM2 role: part[4][j][o] = x @ W3^T (64x64 tile) =====
        const int g2 = blockIdx.x - 2560;
        const int oc2 = g2 & 3, jc2 = g2 >> 2;
        const int j0 = jc2 * 64, o0 = oc2 * 64;
        u16* AL2 = XL;            // 64*72 u16
        u16* BL2 = XL + 8192;     // 64*72 u16
        f32x4 acc2[4] = {};
        for (int t0 = 0; t0 < 512; t0 += 64) {
            __syncthreads();
            #pragma unroll
            for (int c = 0; c < 2; ++c) {
                int cc = tid + c * 256;
                int r = cc >> 3, s = cc & 7;
                *reinterpret_cast<uint4*>(&AL2[r * 72 + s * 8]) =
                    *reinterpret_cast<const uint4*>(Xbf + (size_t)(j0 + r) * 512 + t0 + s * 8);
                *reinterpret_cast<uint4*>(&BL2[r * 72 + s * 8]) =
                    ld8f2b(W3 + (size_t)(o0 + r) * 512 + t0 + s * 8);
            }
            __syncthreads();
            #pragma unroll
            for (int ds = 0; ds < 2; ++ds) {
                bf16x8 afr = *reinterpret_cast<const bf16x8*>(&AL2[(w * 16 + l15) * 72 + ds * 32 + lgp * 8]);
                #pragma unroll
                for (int ot = 0; ot < 4; ++ot) {
                    bf16x8 bfr = *reinterpret_cast<const bf16x8*>(&BL2[(ot * 16 + l15) * 72 + ds * 32 + lgp * 8]);
                    acc2[ot] = __builtin_amdgcn_mfma_f32_16x16x32_bf16(afr, bfr, acc2[ot], 0, 0, 0);
                }
            }
        }
        float* dst = part + (size_t)4 * 512 * 256;
        #pragma unroll
        for (int ot = 0; ot < 4; ++ot)
            #pragma unroll
            for (int i = 0; i < 4; ++i) {
                int rr = j0 + w * 16 + lgp * 4 + i;
                int o = o0 + ot * 16 + l15;
                dst[rr * 256 + o] = acc2[ot][i];
            }
        return;
    }

    if (blockIdx.x >= 2048) {
        // ===== K2m role =====
        const int bx2 = blockIdx.x - 2048;
        const int kh = bx2 & 1;
        const int on = (bx2 >> 1) & 15;
        const int h = (bx2 >> 5) & 7;
        const int b = bx2 >> 8;

        u16* XL2 = XL;
        u16* WL2 = WL;

        const u16* xb = Xbf + b * (T_ * D_) + kh * 128 * D_;
        f32x4 acc[2] = {};
        for (int d0 = 0; d0 < D_; d0 += 64) {
            __syncthreads();
            #pragma unroll
            for (int i = 0; i < 4; ++i) {
                int row = i * 32 + w * 8 + srow_off;
                gload16(xb + row * 512 + d0 + scol, &XL2[i * 2048 + w * 512]);
            }
            if (tid < 128) {
                int r = tid >> 3, s = tid & 7;
                *reinterpret_cast<uint4*>(&WL2[r * 72 + s * 8]) =
                    *reinterpret_cast<const uint4*>(
                        W2t + (size_t)(h * 256 + on * 16 + r) * 512 + d0 + s * 8);
            }
            __syncthreads();
            #pragma unroll
            for (int ds = 0; ds < 2; ++ds) {
                bf16x8 bfr = *reinterpret_cast<const bf16x8*>(&WL2[l15 * 72 + ds * 32 + lgp * 8]);
                #pragma unroll
                for (int kt = 0; kt < 2; ++kt) {
                    int row = w * 32 + kt * 16 + l15;
                    int c16 = ((ds * 4 + lgp) ^ (l15 & 7)) * 8;
                    bf16x8 afr = *reinterpret_cast<const bf16x8*>(&XL2[row * 64 + c16]);
                    acc[kt] = __builtin_amdgcn_mfma_f32_16x16x32_bf16(afr, bfr, acc[kt], 0, 0, 0);
                }
            }
        }
        u16* dst = M + ((size_t)(b * 8 + h) * 256 + on * 16 + l15) * 256 + kh * 128;
        #pragma unroll
        for (int kt = 0; kt < 2; ++kt) {
            uint2 pk;
            pk.x = cvtpk(acc[kt][0], acc[kt][1]);
            pk.y = cvtpk(acc[kt][2], acc[kt][3]);
            *reinterpret_cast<uint2*>(dst + w * 32 + kt * 16 + lgp * 4) = pk;
        }
        return;
    }

    // ===== K1a role =====
    const int oc = blockIdx.x & 3;
    const int j = (blockIdx.x >> 2) & 255;
    const int b = blockIdx.x >> 10;
    const int jt = j >> 6;
    const bool act = (w >= jt);

    const u16* xb = Xbf + b * (T_ * D_);
    const float* xjp = xf + (b * T_ + j) * D_;

    bf16x8 bwreg[2];
    #pragma unroll
    for (int ds = 0; ds < 2; ++ds) {
        u16 awtmp[8];
        #pragma unroll
        for (int e = 0; e < 8; ++e)
            awtmp[e] = (l15 < 8) ? f2b(aw[(oc * 64 + ds * 32 + lgp * 8 + e) * 8 + l15]) : (u16)0;
        bwreg[ds] = *reinterpret_cast<const bf16x8*>(awtmp);
    }

    const int i0 = jt * 2;
    const int wr0 = tid >> 3, wsc = (tid & 7) * 8;
    const int wswz0 = ((tid & 7) ^ (wr0 & 7)) * 8;

    f32x4 acc[4][4] = {};
    for (int d0 = 0; d0 < D_; d0 += 64) {
        __syncthreads();
        #pragma unroll
        for (int i = 0; i < 8; ++i) {
            if (i >= i0) {
                int row = i * 32 + w * 8 + srow_off;
                gload16(xb + row * 512 + d0 + scol, &XL[i * 2048 + w * 512]);
            }
        }
        {
            f32x4 xa = *reinterpret_cast<const f32x4*>(xjp + d0 + wsc);
            f32x4 xc = *reinterpret_cast<const f32x4*>(xjp + d0 + wsc + 4);
            const float* wp0 = Wap + (size_t)(oc * 64 + wr0) * 512 + d0 + wsc;
            f32x4 va = *reinterpret_cast<const f32x4*>(wp0);
            f32x4 vb = *reinterpret_cast<const f32x4*>(wp0 + 4);
            uint4 pk;
            pk.x = cvtpk(va[0] * xa[0], va[1] * xa[1]);
            pk.y = cvtpk(va[2] * xa[2], va[3] * xa[3]);
            pk.z = cvtpk(vb[0] * xc[0], vb[1] * xc[1]);
            pk.w = cvtpk(vb[2] * xc[2], vb[3] * xc[3]);
            *reinterpret_cast<uint4*>(&WL[wr0 * 64 + wswz0]) = pk;
            const float* wp1 = wp0 + 32 * 512;
            va = *reinterpret_cast<const f32x4*>(wp1);
            vb = *reinterpret_cast<const f32x4*>(wp1 + 4);
            pk.x = cvtpk(va[0] * xa[0], va[1] * xa[1]);
            pk.y = cvtpk(va[2] * xa[2], va[3] * xa[3]);
            pk.z = cvtpk(vb[0] * xc[0], vb[1] * xc[1]);
            pk.w = cvtpk(vb[2] * xc[2], vb[3] * xc[3]);
            *reinterpret_cast<uint4*>(&WL[(wr0 + 32) * 64 + wswz0]) = pk;
        }
        __syncthreads();
        if (act) {
            #pragma unroll
            for (int ds = 0; ds < 2; ++ds) {
                bf16x8 wfr[4];
                #pragma unroll
                for (int ot = 0; ot < 4; ++ot) {
                    int wc = ((ds * 4 + lgp) ^ (l15 & 7)) * 8;
                    wfr[ot] = *reinterpret_cast<const bf16x8*>(&WL[(ot * 16 + l15) * 64 + wc]);
                }
                #pragma unroll
                for (int kt = 0; kt < 4; ++kt) {
                    int row = w * 64 + kt * 16 + l15;
                    int c16 = ((ds * 4 + lgp) ^ (l15 & 7)) * 8;
                    bf16x8 xfr = *reinterpret_cast<const bf16x8*>(&XL[row * 64 + c16]);
                    #pragma unroll
                    for (int ot = 0; ot < 4; ++ot)
                        acc[ot][kt] = __builtin_amdgcn_mfma_f32_16x16x32_bf16(wfr[ot], xfr, acc[ot][kt], 0, 0, 0);
                }
            }
        }
    }
    u16* a_lds = XL;
    if (act) {
        #pragma unroll
        for (int ot = 0; ot < 4; ++ot) {
            f32x4 bv = *reinterpret_cast<const f32x4*>(bap + oc * 64 + ot * 16 + lgp * 4);
            #pragma unroll
            for (int kt = 0; kt < 4; ++kt) {
                int k = w * 64 + kt * 16 + l15;
                float t0 = fast_tanh(acc[ot][kt][0] + bv[0]);
                float t1 = fast_tanh(acc[ot][kt][1] + bv[1]);
                float t2 = fast_tanh(acc[ot][kt][2] + bv[2]);
                float t3 = fast_tanh(acc[ot][kt][3] + bv[3]);
                uint2 pk;
                pk.x = cvtpk(t0, t1);
                pk.y = cvtpk(t2, t3);
                int c16 = (ot * 2 + (lgp >> 1)) ^ (l15 & 7);
                *reinterpret_cast<uint2*>(&a_lds[k * 64 + c16 * 8 + (lgp & 1) * 4]) = pk;
            }
        }
    }
    f32x4 attacc[4] = {};
    if (act) {
        #pragma unroll
        for (int ds = 0; ds < 2; ++ds) {
            #pragma unroll
            for (int kt = 0; kt < 4; ++kt) {
                int row = w * 64 + kt * 16 + l15;
                int c16 = ((ds * 4 + lgp) ^ (l15 & 7)) * 8;
                bf16x8 af = *reinterpret_cast<const bf16x8*>(&a_lds[row * 64 + c16]);
                attacc[kt] = __builtin_amdgcn_mfma_f32_16x16x32_bf16(af, bwreg[ds], attacc[kt], 0, 0, 0);
            }
        }
    }
    __syncthreads();
    u16* att_t = WL;   // 256*8 u16 = 4 KB
    if (act && l15 < 8) {
        #pragma unroll
        for (int kt = 0; kt < 4; ++kt) {
            int k0 = w * 64 + kt * 16 + lgp * 4;
            u32 p01 = cvtpk(attacc[kt][0], attacc[kt][1]);
            u32 p23 = cvtpk(attacc[kt][2], attacc[kt][3]);
            att_t[(k0 + 0) * 8 + l15] = (u16)p01;
            att_t[(k0 + 1) * 8 + l15] = (u16)(p01 >> 16);
            att_t[(k0 + 2) * 8 + l15] = (u16)p23;
            att_t[(k0 + 3) * 8 + l15] = (u16)(p23 >> 16);
        }
    }
    __syncthreads();
    {
        int k = tid;
        if (k >= jt * 64) {
            uint4 v = *reinterpret_cast<const uint4*>(&att_t[k * 8]);
            *reinterpret_cast<uint4*>(attp16 + ((size_t)blockIdx.x) * 2048 + k * 8) = v;
            if (k >= (jt + 1) * 64) {
                *reinterpret_cast<uint4*>(
                    attp16 + (((size_t)(b * 256 + k)) * 4 + oc) * 2048 + j * 8) = v;
            }
        }
    }
}

// ---------- K1b: sum 4 bf16 oc-parts + mask + softmax -> P2[b][j][h*256+k] ----------
__global__ void k1b_sm(const u16* __restrict__ attp16, const int* __restrict__ scan_g,
                       u16* __restrict__ P2)
{
    const int b = blockIdx.x >> 8;
    const int j = blockIdx.x & 255;
    const int tid = threadIdx.x;

    __shared__ float attL[256 * 9];
    __shared__ float maskv[256];

    {
        int k = tid;
        const int* sg = scan_g + b * 256;
        float m;
        if (k == j) m = 1.f;
        else if (k > j) m = ((sg[k] - (j ? sg[j - 1] : 0)) == 0) ? 1.f : 0.f;
        else m = ((sg[j] - (k ? sg[k - 1] : 0)) == 0) ? 1.f : 0.f;
        maskv[k] = m;
    }
    {
        const u16* base = attp16 + ((size_t)(b * 256 + j) * 4) * 2048 + tid * 8;
        float s[8] = {};
        #pragma unroll
        for (int oc = 0; oc < 4; ++oc) {
            uint4 v = *reinterpret_cast<const uint4*>(base + (size_t)oc * 2048);
            const u16* p = reinterpret_cast<const u16*>(&v);
            #pragma unroll
            for (int e = 0; e < 8; ++e) s[e] += b2f(p[e]);
        }
        #pragma unroll
        for (int e = 0; e < 8; ++e) attL[tid * 9 + e] = s[e];
    }
    __syncthreads();

    {
        int h = tid >> 5, c = tid & 31;
        float lgv[8];
        float mx = -3.4e38f;
        #pragma unroll
        for (int kk = 0; kk < 8; ++kk) {
            int k = c + kk * 32;
            float v = attL[k * 9 + h] * maskv[k];
            lgv[kk] = v;
            mx = fmaxf(mx, v);
        }
        #pragma unroll
        for (int off = 1; off < 32; off <<= 1)
            mx = fmaxf(mx, __shfl_xor(mx, off, 32));
        float sum = 0.f;
        #pragma unroll
        for (int kk = 0; kk < 8; ++kk) {
            lgv[kk] = __expf(lgv[kk] - mx);
            sum += lgv[kk];
        }
        #pragma unroll
        for (int off = 1; off < 32; off <<= 1)
            sum += __shfl_xor(sum, off, 32);
        float inv = 1.f / sum;
        u16* dst = P2 + ((size_t)(b * 256 + j)) * 2048 + h * 256;
        #pragma unroll
        for (int kk = 0; kk < 8; ++kk)
            dst[c + kk * 32] = f2b(lgv[kk] * inv);
    }
}

// ---------- K3: GEMM1 only (y1 = P2 @ M, split-K) -> part slots 0..3 ----------
__launch_bounds__(256, 4)
__global__ void k3_mm(const u16* __restrict__ P2, const u16* __restrict__ M,
                      float* __restrict__ part)
{
    const int gid = blockIdx.x;
    const int tid = threadIdx.x;
    const int w = tid >> 6, l = tid & 63, l15 = l & 15, lgp = l >> 4;

    __shared__ __align__(16) u16 AL[64 * 72];
    __shared__ __align__(16) u16 BL[64 * 72];

    f32x4 acc[4] = {};
    const int kc = gid & 3;
    const int oc = (gid >> 2) & 3;
    const int jc = gid >> 4;
    const int j0 = jc * 64, o0 = oc * 64;
    const int bb = jc >> 2;
    for (int t = 0; t < 8; ++t) {
        const int hh = kc * 2 + (t >> 2);
        const int k0 = (t & 3) * 64;
        __syncthreads();
        #pragma unroll
        for (int c = 0; c < 2; ++c) {
            int cc = tid + c * 256;
            int r = cc >> 3, s = cc & 7;
            *reinterpret_cast<uint4*>(&AL[r * 72 + s * 8]) =
                *reinterpret_cast<const uint4*>(
                    P2 + (size_t)(j0 + r) * 2048 + hh * 256 + k0 + s * 8);
            *reinterpret_cast<uint4*>(&BL[r * 72 + s * 8]) =
                *reinterpret_cast<const uint4*>(
                    M + ((size_t)(bb * 8 + hh) * 256 + o0 + r) * 256 + k0 + s * 8);
        }
        __syncthreads();
        #pragma unroll
        for (int ds = 0; ds < 2; ++ds) {
            bf16x8 afr = *reinterpret_cast<const bf16x8*>(&AL[(w * 16 + l15) * 72 + ds * 32 + lgp * 8]);
            #pragma unroll
            for (int ot = 0; ot < 4; ++ot) {
                bf16x8 bfr = *reinterpret_cast<const bf16x8*>(&BL[(ot * 16 + l15) * 72 + ds * 32 + lgp * 8]);
                acc[ot] = __builtin_amdgcn_mfma_f32_16x16x32_bf16(afr, bfr, acc[ot], 0, 0, 0);
            }
        }
    }
    float* dst = part + (size_t)kc * 512 * 256;
    #pragma unroll
    for (int ot = 0; ot < 4; ++ot)
        #pragma unroll
        for (int i = 0; i < 4; ++i) {
            int rr = j0 + w * 16 + lgp * 4 + i;
            int o = o0 + ot * 16 + l15;
            dst[rr * 256 + o] = acc[ot][i];
        }
}

// ---------- K4a: combine partials + biases -> ypre, per-chunk BN stats ----------
__global__ void k4a_comb(const float* __restrict__ part,
                         const float* __restrict__ pb2, const float* __restrict__ pb3,
                         float* __restrict__ ypre,
                         float* __restrict__ psum, float* __restrict__ psq)
{
    int g = blockIdx.x, o = threadIdx.x;
    float bsum = pb2[o] + pb3[o];
    float s = 0.f, q = 0.f;
    for (int r = g * 8; r < g * 8 + 8; ++r) {
        size_t idx = (size_t)r * 256 + o;
        float v = part[idx] + part[131072 + idx] + part[2 * 131072 + idx]
                + part[3 * 131072 + idx] + part[4 * 131072 + idx] + bsum;
        ypre[idx] = v;
        s += v; q += v * v;
    }
    psum[g * 256 + o] = s;
    psq[g * 256 + o] = q;
}

// ---------- K4b: fold stats + normalize + affine + SELU -> FP32 output ----------
__global__ void k4b_norm(const float* __restrict__ ypre,
                         const float* __restrict__ psum, const float* __restrict__ psq,
                         const float* __restrict__ gamma, const float* __restrict__ beta,
                         float* __restrict__ out) {
    int r = blockIdx.x, o = threadIdx.x;
    float s = 0.f, q = 0.f;
    #pragma unroll 8
    for (int g = 0; g < 64; ++g) {
        s += psum[g * 256 + o];
        q += psq[g * 256 + o];
    }
    float mu = s * (1.f / 512.f);
    float var = q * (1.f / 512.f) - mu * mu;
    float inv = rsqrtf(var + 1e-5f);
    float v = (ypre[r * 256 + o] - mu) * inv * gamma[o] + beta[o];
    const float SC = 1.0507009873554805f, AL = 1.6732632423543772f;
    float ov = v > 0.f ? SC * v : SC * AL * (__expf(v) - 1.f);
    out[r * 256 + o] = ov;
}

extern "C" void kernel_launch(void* const* d_in, const int* in_sizes, int n_in,
                              void* d_out, int out_size, void* d_ws, size_t ws_size,
                              hipStream_t stream) {
    const float* x    = (const float*)d_in[0];
    const int* bnd    = (const int*)d_in[1];
    const float* Wap  = (const float*)d_in[2];
    const float* bap  = (const float*)d_in[3];
    const float* aw   = (const float*)d_in[4];
    const float* W2   = (const float*)d_in[5];
    const float* pb2  = (const float*)d_in[6];
    const float* W3   = (const float*)d_in[7];
    const float* pb3  = (const float*)d_in[8];
    const float* gamma = (const float*)d_in[9];
    const float* beta  = (const float*)d_in[10];
    float* out = (float*)d_out;
    (void)in_sizes; (void)n_in; (void)out_size; (void)ws_size;

    char* ws = (char*)d_ws;
    u16* Xbf   = (u16*)ws;  ws += (size_t)B_ * T_ * D_ * 2;          // 512 KB
    u16* W2t   = (u16*)ws;  ws += (size_t)H_ * O_ * D_ * 2;          // 2 MB
    u16* P2    = (u16*)ws;  ws += (size_t)B_ * T_ * H_ * T_ * 2;     // 2 MB
    u16* Mbuf  = (u16*)ws;  ws += (size_t)B_ * H_ * O_ * T_ * 2;     // 2 MB
    float* part = (float*)ws; ws += (size_t)5 * 512 * 256 * 4;       // 2.6 MB
    float* ypre = (float*)ws; ws += (size_t)B_ * T_ * O_ * 4;        // 512 KB
    float* psum = (float*)ws; ws += (size_t)64 * O_ * 4;
    float* psq  = (float*)ws; ws += (size_t)64 * O_ * 4;
    int* scan_g = (int*)ws;  ws += (size_t)B_ * T_ * 4;              // 2 KB
    u16* attp16 = (u16*)ws;  ws += (size_t)2048 * 2048 * 2;          // 8.4 MB

    k0_prep<<<194, 256, 0, stream>>>(x, W2, bnd, Xbf, W2t, scan_g);
    k1a_att<<<2592, 256, 0, stream>>>(Xbf, x, Wap, bap, aw, attp16, W2t, Mbuf, W3, part);
    k1b_sm<<<512, 256, 0, stream>>>(attp16, scan_g, P2);
    k3_mm<<<128, 256, 0, stream>>>(P2, Mbuf, part);
    k4a_comb<<<64, 256, 0, stream>>>(part, pb2, pb3, ypre, psum, psq);
    k4b_norm<<<512, 256, 0, stream>>>(ypre, psum, psq, gamma, beta, out);
}

// Round 22
// 80.259 us; speedup vs baseline: 1.0243x; 1.0243x over previous
//
#include <hip/hip_runtime.h>
#include <hip/hip_bf16.h>

// Problem: B=2, T=256, IN_DIM=512, OUT_DIM=256, H=8, TEMP=1, BN_EPS=1e-5
// ROUND 22: revert to round-20 exactly (best: 80.50us). Round-21's GEMM2
// merge regressed (wave-mix interference > launch saving). Final config:
// k0(prep) -> k1a(+k2m merged) -> k1b -> k3 -> k4a -> k4b.
#define B_ 2
#define T_ 256
#define D_ 512
#define O_ 256
#define H_ 8

typedef __attribute__((ext_vector_type(4))) float f32x4;
typedef __attribute__((ext_vector_type(8))) short bf16x8;
typedef unsigned short u16;
typedef unsigned int u32;

__device__ __forceinline__ float b2f(u16 u) {
    u32 t = ((u32)u) << 16;
    return __builtin_bit_cast(float, t);
}
__device__ __forceinline__ u16 f2b(float f) {
    u32 u = __builtin_bit_cast(u32, f);
    u32 r = (u + 0x7FFFu + ((u >> 16) & 1u)) >> 16;  // RNE
    return (u16)r;
}
__device__ __forceinline__ u32 cvtpk(float lo, float hi) {
    u32 r;
    asm("v_cvt_pk_bf16_f32 %0, %1, %2" : "=v"(r) : "v"(lo), "v"(hi));
    return r;
}
__device__ __forceinline__ float fast_tanh(float x) {
    float ax = fabsf(x);
    float e = __expf(-2.f * ax);
    float r = (1.f - e) / (1.f + e);
    return x < 0.f ? -r : r;
}
__device__ __forceinline__ uint4 ld8f2b(const float* __restrict__ p) {
    f32x4 a = *reinterpret_cast<const f32x4*>(p);
    f32x4 b = *reinterpret_cast<const f32x4*>(p + 4);
    uint4 pk;
    pk.x = cvtpk(a[0], a[1]);
    pk.y = cvtpk(a[2], a[3]);
    pk.z = cvtpk(b[0], b[1]);
    pk.w = cvtpk(b[2], b[3]);
    return pk;
}
__device__ __forceinline__ void gload16(const void* g, void* l) {
    __builtin_amdgcn_global_load_lds(
        (const __attribute__((address_space(1))) unsigned int*)g,
        (__attribute__((address_space(3))) unsigned int*)l, 16, 0, 0);
}

// ---------- K0: Xbf (bx<64), W2t (64..191), boundary scan (192..193) ----------
__global__ void k0_prep(const float* __restrict__ x, const float* __restrict__ W2,
                        const int* __restrict__ bnd,
                        u16* __restrict__ Xbf, u16* __restrict__ W2t,
                        int* __restrict__ scan_g) {
    const int tid = threadIdx.x;
    if (blockIdx.x < 64) {
        int base = (blockIdx.x * 256 + tid) * 16;
        uint4 o0 = ld8f2b(x + base);
        uint4 o1 = ld8f2b(x + base + 8);
        *reinterpret_cast<uint4*>(Xbf + base) = o0;
        *reinterpret_cast<uint4*>(Xbf + base + 8) = o1;
        return;
    }
    if (blockIdx.x >= 192) {
        const int b = blockIdx.x - 192;
        __shared__ int sc[256];
        sc[tid] = bnd[b * 256 + tid];
        __syncthreads();
        for (int off = 1; off < 256; off <<= 1) {
            int v = (tid >= off) ? sc[tid - off] : 0;
            __syncthreads();
            sc[tid] += v;
            __syncthreads();
        }
        scan_g[b * 256 + tid] = sc[tid];
        return;
    }
    const int bx2 = blockIdx.x - 64;
    const int o0 = (bx2 >> 3) * 16;
    const int dc = bx2 & 7;
    __shared__ u16 TL[8192];
    #pragma unroll
    for (int c = 0; c < 8; ++c) {
        int i = tid * 32 + c * 4;
        int r = i >> 9, rem = i & 511;
        f32x4 v = *reinterpret_cast<const f32x4*>(
            W2 + (size_t)(o0 + r) * 4096 + dc * 512 + rem);
        int dd = rem >> 3, h0 = rem & 7;
        TL[(h0 + 0) * 1024 + r * 64 + dd] = f2b(v[0]);
        TL[(h0 + 1) * 1024 + r * 64 + dd] = f2b(v[1]);
        TL[(h0 + 2) * 1024 + r * 64 + dd] = f2b(v[2]);
        TL[(h0 + 3) * 1024 + r * 64 + dd] = f2b(v[3]);
    }
    __syncthreads();
    #pragma unroll
    for (int c = 0; c < 4; ++c) {
        int jj = tid * 32 + c * 8;
        int h = jj >> 10, r = (jj >> 6) & 15, dd = jj & 63;
        *reinterpret_cast<uint4*>(W2t + (size_t)(h * 256 + o0 + r) * 512 + dc * 64 + dd) =
            *reinterpret_cast<const uint4*>(&TL[jj]);
    }
}

// ---------- K1a (+merged K2m): blocks <2048 attention; >=2048 M-GEMM ----------
__launch_bounds__(256, 4)
__global__ void k1a_att(const u16* __restrict__ Xbf, const float* __restrict__ xf,
                        const float* __restrict__ Wap, const float* __restrict__ bap,
                        const float* __restrict__ aw, u16* __restrict__ attp16,
                        const u16* __restrict__ W2t, u16* __restrict__ M)
{
    __shared__ __align__(16) u16 XL[256 * 64];   // 32 KB
    __shared__ __align__(16) u16 WL[64 * 64];    // 8 KB (reused as att tile)

    const int tid = threadIdx.x;
    const int w = tid >> 6;
    const int l = tid & 63;
    const int l15 = l & 15;
    const int lgp = l >> 4;
    const int srow_off = (l >> 3);
    const int scol = ((l & 7) ^ ((l >> 3) & 7)) * 8;

    if (blockIdx.x >= 2048) {
        // ===== K2m role =====
        const int bx2 = blockIdx.x - 2048;
        const int kh = bx2 & 1;
        const int on = (bx2 >> 1) & 15;
        const int h = (bx2 >> 5) & 7;
        const int b = bx2 >> 8;

        u16* XL2 = XL;
        u16* WL2 = WL;

        const u16* xb = Xbf + b * (T_ * D_) + kh * 128 * D_;
        f32x4 acc[2] = {};
        for (int d0 = 0; d0 < D_; d0 += 64) {
            __syncthreads();
            #pragma unroll
            for (int i = 0; i < 4; ++i) {
                int row = i * 32 + w * 8 + srow_off;
                gload16(xb + row * 512 + d0 + scol, &XL2[i * 2048 + w * 512]);
            }
            if (tid < 128) {
                int r = tid >> 3, s = tid & 7;
                *reinterpret_cast<uint4*>(&WL2[r * 72 + s * 8]) =
                    *reinterpret_cast<const uint4*>(
                        W2t + (size_t)(h * 256 + on * 16 + r) * 512 + d0 + s * 8);
            }
            __syncthreads();
            #pragma unroll
            for (int ds = 0; ds < 2; ++ds) {
                bf16x8 bfr = *reinterpret_cast<const bf16x8*>(&WL2[l15 * 72 + ds * 32 + lgp * 8]);
                #pragma unroll
                for (int kt = 0; kt < 2; ++kt) {
                    int row = w * 32 + kt * 16 + l15;
                    int c16 = ((ds * 4 + lgp) ^ (l15 & 7)) * 8;
                    bf16x8 afr = *reinterpret_cast<const bf16x8*>(&XL2[row * 64 + c16]);
                    acc[kt] = __builtin_amdgcn_mfma_f32_16x16x32_bf16(afr, bfr, acc[kt], 0, 0, 0);
                }
            }
        }
        u16* dst = M + ((size_t)(b * 8 + h) * 256 + on * 16 + l15) * 256 + kh * 128;
        #pragma unroll
        for (int kt = 0; kt < 2; ++kt) {
            uint2 pk;
            pk.x = cvtpk(acc[kt][0], acc[kt][1]);
            pk.y = cvtpk(acc[kt][2], acc[kt][3]);
            *reinterpret_cast<uint2*>(dst + w * 32 + kt * 16 + lgp * 4) = pk;
        }
        return;
    }

    // ===== K1a role =====
    const int oc = blockIdx.x & 3;
    const int j = (blockIdx.x >> 2) & 255;
    const int b = blockIdx.x >> 10;
    const int jt = j >> 6;
    const bool act = (w >= jt);

    const u16* xb = Xbf + b * (T_ * D_);
    const float* xjp = xf + (b * T_ + j) * D_;

    bf16x8 bwreg[2];
    #pragma unroll
    for (int ds = 0; ds < 2; ++ds) {
        u16 awtmp[8];
        #pragma unroll
        for (int e = 0; e < 8; ++e)
            awtmp[e] = (l15 < 8) ? f2b(aw[(oc * 64 + ds * 32 + lgp * 8 + e) * 8 + l15]) : (u16)0;
        bwreg[ds] = *reinterpret_cast<const bf16x8*>(awtmp);
    }

    const int i0 = jt * 2;
    const int wr0 = tid >> 3, wsc = (tid & 7) * 8;
    const int wswz0 = ((tid & 7) ^ (wr0 & 7)) * 8;

    f32x4 acc[4][4] = {};
    for (int d0 = 0; d0 < D_; d0 += 64) {
        __syncthreads();
        #pragma unroll
        for (int i = 0; i < 8; ++i) {
            if (i >= i0) {
                int row = i * 32 + w * 8 + srow_off;
                gload16(xb + row * 512 + d0 + scol, &XL[i * 2048 + w * 512]);
            }
        }
        {
            f32x4 xa = *reinterpret_cast<const f32x4*>(xjp + d0 + wsc);
            f32x4 xc = *reinterpret_cast<const f32x4*>(xjp + d0 + wsc + 4);
            const float* wp0 = Wap + (size_t)(oc * 64 + wr0) * 512 + d0 + wsc;
            f32x4 va = *reinterpret_cast<const f32x4*>(wp0);
            f32x4 vb = *reinterpret_cast<const f32x4*>(wp0 + 4);
            uint4 pk;
            pk.x = cvtpk(va[0] * xa[0], va[1] * xa[1]);
            pk.y = cvtpk(va[2] * xa[2], va[3] * xa[3]);
            pk.z = cvtpk(vb[0] * xc[0], vb[1] * xc[1]);
            pk.w = cvtpk(vb[2] * xc[2], vb[3] * xc[3]);
            *reinterpret_cast<uint4*>(&WL[wr0 * 64 + wswz0]) = pk;
            const float* wp1 = wp0 + 32 * 512;
            va = *reinterpret_cast<const f32x4*>(wp1);
            vb = *reinterpret_cast<const f32x4*>(wp1 + 4);
            pk.x = cvtpk(va[0] * xa[0], va[1] * xa[1]);
            pk.y = cvtpk(va[2] * xa[2], va[3] * xa[3]);
            pk.z = cvtpk(vb[0] * xc[0], vb[1] * xc[1]);
            pk.w = cvtpk(vb[2] * xc[2], vb[3] * xc[3]);
            *reinterpret_cast<uint4*>(&WL[(wr0 + 32) * 64 + wswz0]) = pk;
        }
        __syncthreads();
        if (act) {
            #pragma unroll
            for (int ds = 0; ds < 2; ++ds) {
                bf16x8 wfr[4];
                #pragma unroll
                for (int ot = 0; ot < 4; ++ot) {
                    int wc = ((ds * 4 + lgp) ^ (l15 & 7)) * 8;
                    wfr[ot] = *reinterpret_cast<const bf16x8*>(&WL[(ot * 16 + l15) * 64 + wc]);
                }
                #pragma unroll
                for (int kt = 0; kt < 4; ++kt) {
                    int row = w * 64 + kt * 16 + l15;
                    int c16 = ((ds * 4 + lgp) ^ (l15 & 7)) * 8;
                    bf16x8 xfr = *reinterpret_cast<const bf16x8*>(&XL[row * 64 + c16]);
                    #pragma unroll
                    for (int ot = 0; ot < 4; ++ot)
                        acc[ot][kt] = __builtin_amdgcn_mfma_f32_16x16x32_bf16(wfr[ot], xfr, acc[ot][kt], 0, 0, 0);
                }
            }
        }
    }
    u16* a_lds = XL;
    if (act) {
        #pragma unroll
        for (int ot = 0; ot < 4; ++ot) {
            f32x4 bv = *reinterpret_cast<const f32x4*>(bap + oc * 64 + ot * 16 + lgp * 4);
            #pragma unroll
            for (int kt = 0; kt < 4; ++kt) {
                int k = w * 64 + kt * 16 + l15;
                float t0 = fast_tanh(acc[ot][kt][0] + bv[0]);
                float t1 = fast_tanh(acc[ot][kt][1] + bv[1]);
                float t2 = fast_tanh(acc[ot][kt][2] + bv[2]);
                float t3 = fast_tanh(acc[ot][kt][3] + bv[3]);
                uint2 pk;
                pk.x = cvtpk(t0, t1);
                pk.y = cvtpk(t2, t3);
                int c16 = (ot * 2 + (lgp >> 1)) ^ (l15 & 7);
                *reinterpret_cast<uint2*>(&a_lds[k * 64 + c16 * 8 + (lgp & 1) * 4]) = pk;
            }
        }
    }
    f32x4 attacc[4] = {};
    if (act) {
        #pragma unroll
        for (int ds = 0; ds < 2; ++ds) {
            #pragma unroll
            for (int kt = 0; kt < 4; ++kt) {
                int row = w * 64 + kt * 16 + l15;
                int c16 = ((ds * 4 + lgp) ^ (l15 & 7)) * 8;
                bf16x8 af = *reinterpret_cast<const bf16x8*>(&a_lds[row * 64 + c16]);
                attacc[kt] = __builtin_amdgcn_mfma_f32_16x16x32_bf16(af, bwreg[ds], attacc[kt], 0, 0, 0);
            }
        }
    }
    // stage att[k][h] (bf16) into WL, then coalesced uint4 direct+mirror writes
    __syncthreads();   // all waves done reading WL (main loop)
    u16* att_t = WL;   // 256*8 u16 = 4 KB
    if (act && l15 < 8) {
        #pragma unroll
        for (int kt = 0; kt < 4; ++kt) {
            int k0 = w * 64 + kt * 16 + lgp * 4;
            u32 p01 = cvtpk(attacc[kt][0], attacc[kt][1]);
            u32 p23 = cvtpk(attacc[kt][2], attacc[kt][3]);
            att_t[(k0 + 0) * 8 + l15] = (u16)p01;
            att_t[(k0 + 1) * 8 + l15] = (u16)(p01 >> 16);
            att_t[(k0 + 2) * 8 + l15] = (u16)p23;
            att_t[(k0 + 3) * 8 + l15] = (u16)(p23 >> 16);
        }
    }
    __syncthreads();
    {
        int k = tid;
        if (k >= jt * 64) {
            uint4 v = *reinterpret_cast<const uint4*>(&att_t[k * 8]);
            *reinterpret_cast<uint4*>(attp16 + ((size_t)blockIdx.x) * 2048 + k * 8) = v;
            if (k >= (jt + 1) * 64) {
                *reinterpret_cast<uint4*>(
                    attp16 + (((size_t)(b * 256 + k)) * 4 + oc) * 2048 + j * 8) = v;
            }
        }
    }
}

// ---------- K1b: sum 4 bf16 oc-parts + mask + softmax -> P2[b][j][h*256+k] ----------
__global__ void k1b_sm(const u16* __restrict__ attp16, const int* __restrict__ scan_g,
                       u16* __restrict__ P2)
{
    const int b = blockIdx.x >> 8;
    const int j = blockIdx.x & 255;
    const int tid = threadIdx.x;

    __shared__ float attL[256 * 9];
    __shared__ float maskv[256];

    {
        int k = tid;
        const int* sg = scan_g + b * 256;
        float m;
        if (k == j) m = 1.f;
        else if (k > j) m = ((sg[k] - (j ? sg[j - 1] : 0)) == 0) ? 1.f : 0.f;
        else m = ((sg[j] - (k ? sg[k - 1] : 0)) == 0) ? 1.f : 0.f;
        maskv[k] = m;
    }
    {
        const u16* base = attp16 + ((size_t)(b * 256 + j) * 4) * 2048 + tid * 8;
        float s[8] = {};
        #pragma unroll
        for (int oc = 0; oc < 4; ++oc) {
            uint4 v = *reinterpret_cast<const uint4*>(base + (size_t)oc * 2048);
            const u16* p = reinterpret_cast<const u16*>(&v);
            #pragma unroll
            for (int e = 0; e < 8; ++e) s[e] += b2f(p[e]);
        }
        #pragma unroll
        for (int e = 0; e < 8; ++e) attL[tid * 9 + e] = s[e];
    }
    __syncthreads();

    {
        int h = tid >> 5, c = tid & 31;
        float lgv[8];
        float mx = -3.4e38f;
        #pragma unroll
        for (int kk = 0; kk < 8; ++kk) {
            int k = c + kk * 32;
            float v = attL[k * 9 + h] * maskv[k];
            lgv[kk] = v;
            mx = fmaxf(mx, v);
        }
        #pragma unroll
        for (int off = 1; off < 32; off <<= 1)
            mx = fmaxf(mx, __shfl_xor(mx, off, 32));
        float sum = 0.f;
        #pragma unroll
        for (int kk = 0; kk < 8; ++kk) {
            lgv[kk] = __expf(lgv[kk] - mx);
            sum += lgv[kk];
        }
        #pragma unroll
        for (int off = 1; off < 32; off <<= 1)
            sum += __shfl_xor(sum, off, 32);
        float inv = 1.f / sum;
        u16* dst = P2 + ((size_t)(b * 256 + j)) * 2048 + h * 256;
        #pragma unroll
        for (int kk = 0; kk < 8; ++kk)
            dst[c + kk * 32] = f2b(lgv[kk] * inv);
    }
}

// ---------- K3: split-K projections -> 5 partial buffers ----------
__launch_bounds__(256, 4)
__global__ void k3_mm(const u16* __restrict__ P2, const u16* __restrict__ M,
                      const u16* __restrict__ Xbf, const float* __restrict__ W3,
                      float* __restrict__ part)
{
    const int gid = blockIdx.x;
    const int tid = threadIdx.x;
    const int w = tid >> 6, l = tid & 63, l15 = l & 15, lgp = l >> 4;

    __shared__ __align__(16) u16 AL[64 * 72];
    __shared__ __align__(16) u16 BL[64 * 72];

    f32x4 acc[4] = {};
    int jc, oc, slot;
    if (gid < 128) {
        int kc = gid & 3;
        oc = (gid >> 2) & 3;
        jc = gid >> 4;
        slot = kc;
        const int j0 = jc * 64, o0 = oc * 64;
        const int bb = jc >> 2;
        for (int t = 0; t < 8; ++t) {
            const int hh = kc * 2 + (t >> 2);
            const int k0 = (t & 3) * 64;
            __syncthreads();
            #pragma unroll
            for (int c = 0; c < 2; ++c) {
                int cc = tid + c * 256;
                int r = cc >> 3, s = cc & 7;
                *reinterpret_cast<uint4*>(&AL[r * 72 + s * 8]) =
                    *reinterpret_cast<const uint4*>(
                        P2 + (size_t)(j0 + r) * 2048 + hh * 256 + k0 + s * 8);
                *reinterpret_cast<uint4*>(&BL[r * 72 + s * 8]) =
                    *reinterpret_cast<const uint4*>(
                        M + ((size_t)(bb * 8 + hh) * 256 + o0 + r) * 256 + k0 + s * 8);
            }
            __syncthreads();
            #pragma unroll
            for (int ds = 0; ds < 2; ++ds) {
                bf16x8 afr = *reinterpret_cast<const bf16x8*>(&AL[(w * 16 + l15) * 72 + ds * 32 + lgp * 8]);
                #pragma unroll
                for (int ot = 0; ot < 4; ++ot) {
                    bf16x8 bfr = *reinterpret_cast<const bf16x8*>(&BL[(ot * 16 + l15) * 72 + ds * 32 + lgp * 8]);
                    acc[ot] = __builtin_amdgcn_mfma_f32_16x16x32_bf16(afr, bfr, acc[ot], 0, 0, 0);
                }
            }
        }
    } else {
        int g2 = gid - 128;
        oc = g2 & 3;
        jc = g2 >> 2;
        slot = 4;
        const int j0 = jc * 64, o0 = oc * 64;
        for (int t0 = 0; t0 < 512; t0 += 64) {
            __syncthreads();
            #pragma unroll
            for (int c = 0; c < 2; ++c) {
                int cc = tid + c * 256;
                int r = cc >> 3, s = cc & 7;
                *reinterpret_cast<uint4*>(&AL[r * 72 + s * 8]) =
                    *reinterpret_cast<const uint4*>(Xbf + (size_t)(j0 + r) * 512 + t0 + s * 8);
                *reinterpret_cast<uint4*>(&BL[r * 72 + s * 8]) =
                    ld8f2b(W3 + (size_t)(o0 + r) * 512 + t0 + s * 8);
            }
            __syncthreads();
            #pragma unroll
            for (int ds = 0; ds < 2; ++ds) {
                bf16x8 afr = *reinterpret_cast<const bf16x8*>(&AL[(w * 16 + l15) * 72 + ds * 32 + lgp * 8]);
                #pragma unroll
                for (int ot = 0; ot < 4; ++ot) {
                    bf16x8 bfr = *reinterpret_cast<const bf16x8*>(&BL[(ot * 16 + l15) * 72 + ds * 32 + lgp * 8]);
                    acc[ot] = __builtin_amdgcn_mfma_f32_16x16x32_bf16(afr, bfr, acc[ot], 0, 0, 0);
                }
            }
        }
    }
    const int j0 = jc * 64, o0 = oc * 64;
    float* dst = part + (size_t)slot * 512 * 256;
    #pragma unroll
    for (int ot = 0; ot < 4; ++ot)
        #pragma unroll
        for (int i = 0; i < 4; ++i) {
            int rr = j0 + w * 16 + lgp * 4 + i;
            int o = o0 + ot * 16 + l15;
            dst[rr * 256 + o] = acc[ot][i];
        }
}

// ---------- K4a: combine partials + biases -> ypre, per-chunk BN stats ----------
__global__ void k4a_comb(const float* __restrict__ part,
                         const float* __restrict__ pb2, const float* __restrict__ pb3,
                         float* __restrict__ ypre,
                         float* __restrict__ psum, float* __restrict__ psq)
{
    int g = blockIdx.x, o = threadIdx.x;
    float bsum = pb2[o] + pb3[o];
    float s = 0.f, q = 0.f;
    for (int r = g * 8; r < g * 8 + 8; ++r) {
        size_t idx = (size_t)r * 256 + o;
        float v = part[idx] + part[131072 + idx] + part[2 * 131072 + idx]
                + part[3 * 131072 + idx] + part[4 * 131072 + idx] + bsum;
        ypre[idx] = v;
        s += v; q += v * v;
    }
    psum[g * 256 + o] = s;
    psq[g * 256 + o] = q;
}

// ---------- K4b: fold stats + normalize + affine + SELU -> FP32 output ----------
__global__ void k4b_norm(const float* __restrict__ ypre,
                         const float* __restrict__ psum, const float* __restrict__ psq,
                         const float* __restrict__ gamma, const float* __restrict__ beta,
                         float* __restrict__ out) {
    int r = blockIdx.x, o = threadIdx.x;
    float s = 0.f, q = 0.f;
    #pragma unroll 8
    for (int g = 0; g < 64; ++g) {
        s += psum[g * 256 + o];
        q += psq[g * 256 + o];
    }
    float mu = s * (1.f / 512.f);
    float var = q * (1.f / 512.f) - mu * mu;
    float inv = rsqrtf(var + 1e-5f);
    float v = (ypre[r * 256 + o] - mu) * inv * gamma[o] + beta[o];
    const float SC = 1.0507009873554805f, AL = 1.6732632423543772f;
    float ov = v > 0.f ? SC * v : SC * AL * (__expf(v) - 1.f);
    out[r * 256 + o] = ov;
}

extern "C" void kernel_launch(void* const* d_in, const int* in_sizes, int n_in,
                              void* d_out, int out_size, void* d_ws, size_t ws_size,
                              hipStream_t stream) {
    const float* x    = (const float*)d_in[0];
    const int* bnd    = (const int*)d_in[1];
    const float* Wap  = (const float*)d_in[2];
    const float* bap  = (const float*)d_in[3];
    const float* aw   = (const float*)d_in[4];
    const float* W2   = (const float*)d_in[5];
    const float* pb2  = (const float*)d_in[6];
    const float* W3   = (const float*)d_in[7];
    const float* pb3  = (const float*)d_in[8];
    const float* gamma = (const float*)d_in[9];
    const float* beta  = (const float*)d_in[10];
    float* out = (float*)d_out;
    (void)in_sizes; (void)n_in; (void)out_size; (void)ws_size;

    char* ws = (char*)d_ws;
    u16* Xbf   = (u16*)ws;  ws += (size_t)B_ * T_ * D_ * 2;          // 512 KB
    u16* W2t   = (u16*)ws;  ws += (size_t)H_ * O_ * D_ * 2;          // 2 MB
    u16* P2    = (u16*)ws;  ws += (size_t)B_ * T_ * H_ * T_ * 2;     // 2 MB
    u16* Mbuf  = (u16*)ws;  ws += (size_t)B_ * H_ * O_ * T_ * 2;     // 2 MB
    float* part = (float*)ws; ws += (size_t)5 * 512 * 256 * 4;       // 2.6 MB
    float* ypre = (float*)ws; ws += (size_t)B_ * T_ * O_ * 4;        // 512 KB
    float* psum = (float*)ws; ws += (size_t)64 * O_ * 4;
    float* psq  = (float*)ws; ws += (size_t)64 * O_ * 4;
    int* scan_g = (int*)ws;  ws += (size_t)B_ * T_ * 4;              // 2 KB
    u16* attp16 = (u16*)ws;  ws += (size_t)2048 * 2048 * 2;          // 8.4 MB

    k0_prep<<<194, 256, 0, stream>>>(x, W2, bnd, Xbf, W2t, scan_g);
    k1a_att<<<2560, 256, 0, stream>>>(Xbf, x, Wap, bap, aw, attp16, W2t, Mbuf);
    k1b_sm<<<512, 256, 0, stream>>>(attp16, scan_g, P2);
    k3_mm<<<160, 256, 0, stream>>>(P2, Mbuf, Xbf, W3, part);
    k4a_comb<<<64, 256, 0, stream>>>(part, pb2, pb3, ypre, psum, psq);
    k4b_norm<<<512, 256, 0, stream>>>(ypre, psum, psq, gamma, beta, out);
}